// Round 7
// baseline (245.628 us; speedup 1.0000x reference)
//
#include <hip/hip_runtime.h>
#include <hip/hip_bf16.h>
#include <stdint.h>

// ---------------------------------------------------------------------------
// MHA: B=2, S=4096, D=512, H=8, dk=64.
// R16: flash is LDS-read-bound (2.1 GB of ds_read ≈ 40 µs at 85 B/cyc —
// dominates the 9 µs MFMA floor). Fix: V bypasses LDS — each wave
// global_load_dwordx4's its V fragments straight from L2 (layout already
// lane-coalesced), K-only staging (4 x 8KB bufs). LDS reads halve; V stream
// rides the L2 pipe in parallel. V loads issue BEFORE the stage16s so
// compiler waits are vmcnt(6)/vmcnt(2) and staging never drains mid-step.
// proj3/proj_o/cvt: R15-proven versions unchanged.
// ---------------------------------------------------------------------------

typedef float  floatx4 __attribute__((ext_vector_type(4)));
typedef __bf16 bf16x8  __attribute__((ext_vector_type(8)));
typedef short  shortx4 __attribute__((ext_vector_type(4)));

#define MFMA16(a, b, c) __builtin_amdgcn_mfma_f32_16x16x32_bf16((a), (b), (c), 0, 0, 0)

// folded into Q projection: (1/sqrt(64)) * log2(e)  -> scores in log2 domain
#define QSCALE 0.1803368801111244f

__device__ __forceinline__ short f2bf(float f) {   // RNE
  union { float f; uint32_t u; } a; a.f = f;
  uint32_t u = a.u;
  u += 0x7fffu + ((u >> 16) & 1u);
  return (short)(u >> 16);
}

// async global->LDS, 16B per lane; lds dest = wave-uniform base + lane*16
__device__ __forceinline__ void stage16(const short* g, short* l) {
  __builtin_amdgcn_global_load_lds(
      (const __attribute__((address_space(1))) void*)g,
      (__attribute__((address_space(3))) void*)l, 16, 0, 0);
}

// ---------------------------------------------------------------------------
// fp32 -> bf16 activations (q,k,v), blockIdx.y picks tensor
// ---------------------------------------------------------------------------
__global__ __launch_bounds__(256) void cvt3_kernel(const float* __restrict__ q,
                                                   const float* __restrict__ k,
                                                   const float* __restrict__ v,
                                                   short* __restrict__ out, int n4) {
  const int which = blockIdx.y;
  const float* in = which == 0 ? q : which == 1 ? k : v;
  short* o = out + (size_t)which * (size_t)n4 * 4;
  int i = blockIdx.x * 256 + threadIdx.x;
  if (i < n4) {
    float4 f = reinterpret_cast<const float4*>(in)[i];
    shortx4 s;
    s.x = f2bf(f.x); s.y = f2bf(f.y); s.z = f2bf(f.z); s.w = f2bf(f.w);
    reinterpret_cast<shortx4*>(o)[i] = s;
  }
}

// weights fp32 -> bf16, blockIdx.y picks tensor
__global__ __launch_bounds__(256) void cvtw_kernel(const float* __restrict__ w0,
                                                   const float* __restrict__ w1,
                                                   const float* __restrict__ w2,
                                                   const float* __restrict__ w3,
                                                   short* __restrict__ out, int n4) {
  const int which = blockIdx.y;
  const float* in = which == 0 ? w0 : which == 1 ? w1 : which == 2 ? w2 : w3;
  short* o = out + (size_t)which * (size_t)n4 * 4;
  int i = blockIdx.x * 256 + threadIdx.x;
  if (i < n4) {
    float4 f = reinterpret_cast<const float4*>(in)[i];
    shortx4 s;
    s.x = f2bf(f.x); s.y = f2bf(f.y); s.z = f2bf(f.z); s.w = f2bf(f.w);
    reinterpret_cast<shortx4*>(o)[i] = s;
  }
}

// ---------------------------------------------------------------------------
// Fused Q/K/V projection. blockIdx.z picks tensor. A[8192,512] x W[512,512]^T.
// 128x64 tile, BK=32, double-buffered LDS (global_load_lds, 1 barrier/iter),
// XOR-swizzled fragment reads (cell(row,q) at chunk q ^ ((row^(row>>2))&3)).
// Epilogues: Q scaled log2-domain; K/V fragment/lane-ordered (slot = g).
// ---------------------------------------------------------------------------
__global__ __launch_bounds__(256) void proj3_kernel(
    const short* __restrict__ xq, const short* __restrict__ xk, const short* __restrict__ xv,
    const short* __restrict__ wq, const short* __restrict__ wk, const short* __restrict__ wv,
    const float* __restrict__ bq, const float* __restrict__ bk, const float* __restrict__ bv,
    short* __restrict__ Qh, short* __restrict__ KV) {
  const int which = blockIdx.z;
  const short* A = which == 0 ? xq : which == 1 ? xk : xv;
  const short* W = which == 0 ? wq : which == 1 ? wk : wv;
  const float* bias = which == 0 ? bq : which == 1 ? bk : bv;

  __shared__ __align__(16) short sA[2][4096];   // [128][32] swizzled
  __shared__ __align__(16) short sB[2][2048];   // [64][32] swizzled

  const int K = 512;
  const int tid = threadIdx.x;
  const int lane = tid & 63;
  const int wave = tid >> 6;
  const int l15 = lane & 15;
  const int quad = lane >> 4;
  const int tileM = blockIdx.x * 128;
  const int tileN = blockIdx.y * 64;

  const int srow = tid >> 2;                       // 0..63
  const int fr = (srow ^ (srow >> 2)) & 3;         // same for srow+64
  const int sq = ((tid & 3) ^ fr) * 8;
  const short* As0 = A + (size_t)(tileM + srow) * K + sq;        // rows 0..63
  const short* As1 = As0 + (size_t)64 * K;                       // rows 64..127
  const short* Bs  = W + (size_t)(tileN + srow) * K + sq;
  const int ldw = wave * 512;                      // wave-uniform LDS slice (shorts)

  const int fl = (l15 ^ (l15 >> 2)) & 3;
  const int qsw = (quad ^ fl) * 8;
  const int ra0 = (wave * 32 + l15) * 32 + qsw;    // A frag mt=0
  const int ra1 = ra0 + 512;                       // mt=1 (+16 rows)
  const int rb0 = l15 * 32 + qsw;                  // B frag (+ nt*512)

  floatx4 acc[2][4];
#pragma unroll
  for (int mt = 0; mt < 2; ++mt)
#pragma unroll
    for (int nt = 0; nt < 4; ++nt) acc[mt][nt] = (floatx4){0.f, 0.f, 0.f, 0.f};

  // prologue: stage k-slice 0 into buffer 0
  stage16(As0, &sA[0][ldw]);
  stage16(As1, &sA[0][2048 + ldw]);
  stage16(Bs,  &sB[0][ldw]);

#pragma unroll 2
  for (int t = 0; t < 16; ++t) {
    __syncthreads();                 // drains own stage vmcnt + block sync
    if (t != 15) {                   // stage next slice into other buffer
      const int kk = (t + 1) * 32;
      short* a_ld = &sA[(t + 1) & 1][ldw];
      stage16(As0 + kk, a_ld);
      stage16(As1 + kk, a_ld + 2048);
      stage16(Bs + kk, &sB[(t + 1) & 1][ldw]);
    }
    const short* sa = sA[t & 1];
    const short* sb = sB[t & 1];
    bf16x8 a0 = *(const bf16x8*)&sa[ra0];
    bf16x8 a1 = *(const bf16x8*)&sa[ra1];
#pragma unroll
    for (int nt = 0; nt < 4; ++nt) {
      bf16x8 wf = *(const bf16x8*)&sb[rb0 + nt * 512];
      acc[0][nt] = MFMA16(a0, wf, acc[0][nt]);
      acc[1][nt] = MFMA16(a1, wf, acc[1][nt]);
    }
  }

#pragma unroll
  for (int mt = 0; mt < 2; ++mt) {
    const int rowbase = tileM + wave * 32 + mt * 16 + quad * 4;  // C/D row = quad*4+reg
    const int b = rowbase >> 12, s = rowbase & 4095;
    const int g = s >> 5;
    if (which == 0) {
      // Q: [bh][s][64], scaled into log2 domain
#pragma unroll
      for (int nt = 0; nt < 4; ++nt) {
        const int col = tileN + nt * 16 + l15;
        const int h = col >> 6, d = col & 63;
        const float bc = bias[col];
#pragma unroll
        for (int r = 0; r < 4; ++r) {
          const int row = rowbase + r;
          const int ss = row & 4095;
          Qh[(size_t)((b * 8 + h) * 4096 + ss) * 64 + d] = f2bf((acc[mt][nt][r] + bc) * QSCALE);
        }
      }
    } else if (which == 1) {
      // K fragment chunks (lane-ordered: region*512 + quadk*128 + key15*8 + j)
      const int key = s & 31;
      const int tt = key >> 4;
      const int l15b = key & 15;                 // +r, stays <16
#pragma unroll
      for (int nt = 0; nt < 4; ++nt) {
        const int col = tileN + nt * 16 + l15;
        const int h = col >> 6, dd = col & 63;
        const int ks = dd >> 5, quadk = (dd >> 3) & 3, jj = dd & 7;
        const float bc = bias[col];
        const size_t base = ((size_t)(b * 8 + h) * 128 + g) * 4096 +
                            (size_t)(tt * 2 + ks) * 512 + (size_t)quadk * 128 + jj;
#pragma unroll
        for (int r = 0; r < 4; ++r)
          KV[base + (size_t)(l15b + r) * 8] = f2bf(acc[mt][nt][r] + bc);
      }
    } else {
      // V fragment chunks (lane-ordered: 2048 + dt*512 + quadv*128 + d15*8 + j)
      const int p32 = s & 31;                    // multiple of 4
      const int l0 = ((p32 & 15) >> 2) * 8 + (p32 >> 4) * 4;
      const int quadv = l0 >> 3, jv = l0 & 7;    // jv in {0,4}
#pragma unroll
      for (int nt = 0; nt < 4; ++nt) {
        const int col = tileN + nt * 16 + l15;
        const int h = col >> 6, dd = col & 63;
        const int dt = dd >> 4, l15v = dd & 15;
        const float bc = bias[col];
        shortx4 p;
        p.x = f2bf(acc[mt][nt][0] + bc);
        p.y = f2bf(acc[mt][nt][1] + bc);
        p.z = f2bf(acc[mt][nt][2] + bc);
        p.w = f2bf(acc[mt][nt][3] + bc);
        *(shortx4*)(KV + ((size_t)(b * 8 + h) * 128 + g) * 4096 + 2048 +
                    (size_t)dt * 512 + (size_t)quadv * 128 + (size_t)l15v * 8 + jv) = p;
      }
    }
  }
}

// ---------------------------------------------------------------------------
// Output projection: ctx bf16 [8192,512] x Wo^T + bo -> fp32 out. 128x64.
// ---------------------------------------------------------------------------
__global__ __launch_bounds__(256) void proj_o_kernel(
    const short* __restrict__ A, const short* __restrict__ W,
    const float* __restrict__ bias, float* __restrict__ out) {
  __shared__ __align__(16) short sA[2][4096];
  __shared__ __align__(16) short sB[2][2048];

  const int K = 512;
  const int tid = threadIdx.x;
  const int lane = tid & 63;
  const int wave = tid >> 6;
  const int l15 = lane & 15;
  const int quad = lane >> 4;
  const int tileM = blockIdx.x * 128;
  const int tileN = blockIdx.y * 64;

  const int srow = tid >> 2;
  const int fr = (srow ^ (srow >> 2)) & 3;
  const int sq = ((tid & 3) ^ fr) * 8;
  const short* As0 = A + (size_t)(tileM + srow) * K + sq;
  const short* As1 = As0 + (size_t)64 * K;
  const short* Bs  = W + (size_t)(tileN + srow) * K + sq;
  const int ldw = wave * 512;

  const int fl = (l15 ^ (l15 >> 2)) & 3;
  const int qsw = (quad ^ fl) * 8;
  const int ra0 = (wave * 32 + l15) * 32 + qsw;
  const int ra1 = ra0 + 512;
  const int rb0 = l15 * 32 + qsw;

  floatx4 acc[2][4];
#pragma unroll
  for (int mt = 0; mt < 2; ++mt)
#pragma unroll
    for (int nt = 0; nt < 4; ++nt) acc[mt][nt] = (floatx4){0.f, 0.f, 0.f, 0.f};

  stage16(As0, &sA[0][ldw]);
  stage16(As1, &sA[0][2048 + ldw]);
  stage16(Bs,  &sB[0][ldw]);

#pragma unroll 2
  for (int t = 0; t < 16; ++t) {
    __syncthreads();
    if (t != 15) {
      const int kk = (t + 1) * 32;
      short* a_ld = &sA[(t + 1) & 1][ldw];
      stage16(As0 + kk, a_ld);
      stage16(As1 + kk, a_ld + 2048);
      stage16(Bs + kk, &sB[(t + 1) & 1][ldw]);
    }
    const short* sa = sA[t & 1];
    const short* sb = sB[t & 1];
    bf16x8 a0 = *(const bf16x8*)&sa[ra0];
    bf16x8 a1 = *(const bf16x8*)&sa[ra1];
#pragma unroll
    for (int nt = 0; nt < 4; ++nt) {
      bf16x8 wf = *(const bf16x8*)&sb[rb0 + nt * 512];
      acc[0][nt] = MFMA16(a0, wf, acc[0][nt]);
      acc[1][nt] = MFMA16(a1, wf, acc[1][nt]);
    }
  }

#pragma unroll
  for (int mt = 0; mt < 2; ++mt) {
    const int rowbase = tileM + wave * 32 + mt * 16 + quad * 4;
#pragma unroll
    for (int nt = 0; nt < 4; ++nt) {
      const int col = tileN + nt * 16 + l15;
      const float bc = bias[col];
#pragma unroll
      for (int r = 0; r < 4; ++r) out[(size_t)(rowbase + r) * 512 + col] = acc[mt][nt][r] + bc;
    }
  }
}

// ---------------------------------------------------------------------------
// Flash attention: 8 waves (4 qg x 2 key-half). K-only LDS staging (4 x 8KB
// bufs = pairs of key-groups), V read per-wave from global/L2 (coalesced
// dwordx4). Per step: vmcnt(0)+lgkmcnt(0) -> s_barrier -> issue 8 V loads
// (both groups) -> stage 2 K-pairs -> setprio(1) COMPUTE x2 setprio(0).
// V loads precede stage16s so the compiler's waits (vmcnt 6/2) never drain
// the staging queue mid-step. Combine through separate comb array.
// ---------------------------------------------------------------------------
__global__ __launch_bounds__(512) void flash_kernel(
    const short* __restrict__ Qh, const short* __restrict__ KV,
    short* __restrict__ ctx) {
  __shared__ __align__(16) short sK[4][4096];    // 4 bufs x 8KB (K of 2 groups)
  __shared__ float comb[4][64][34];              // half=1 partials (o:32, l:2)

  const int id = blockIdx.x;          // 0..511
  const int xcd = id & 7;
  const int j = id >> 3;              // 0..63
  const int bh = xcd + ((j >> 5) << 3);
  const int qtile = j & 31;

  const int tid = threadIdx.x;
  const int wave = tid >> 6;          // 0..7
  const int lane = tid & 63;
  const int l15 = lane & 15;
  const int quad = lane >> 4;
  const int wq = wave & 3;            // q-row group within block
  const int half = wave >> 2;         // key half: 0 -> even groups, 1 -> odd
  const int qrow0 = qtile * 128 + wq * 32;

  // Q B-frags: B[k=d=quad*8+i+32ks][n=qrow=l15]
  bf16x8 qf[2][2];
#pragma unroll
  for (int nt = 0; nt < 2; ++nt) {
    const short* Qb = Qh + (size_t)(bh * 4096 + qrow0 + nt * 16 + l15) * 64 + quad * 8;
    qf[nt][0] = *(const bf16x8*)(Qb);
    qf[nt][1] = *(const bf16x8*)(Qb + 32);
  }

  // ones A-fragment (bf16 1.0 = 0x3F80) for MFMA row-sums
  bf16x8 ones;
  {
    union { short s[8]; bf16x8 v; } u;
#pragma unroll
    for (int i = 0; i < 8; ++i) u.s[i] = (short)0x3F80;
    ones = u.v;
  }

  const short* KVb = KV + (size_t)bh * (128 * 4096);
  // K staging src for pair p (pair = groups 2p,2p+1; K regions only):
  //   wave w covers 1KB: global shorts p*8192 + (w&3)*512 + (w>>2)*4096
  const short* sgK = KVb + (size_t)(wave & 3) * 512 + (size_t)(wave >> 2) * 4096 + lane * 8;
  const int ldw = wave * 512;                       // buf dest offset (shorts)
  const int av = lane * 8;                          // lane-ordered chunk address
  const short* gV = KVb + 2048 + lane * 8;          // V base (+ g*4096 + j*512)

  const floatx4 FZ = (floatx4){0.f, 0.f, 0.f, 0.f};
  floatx4 o[2][4];
  floatx4 lacc[2];
#pragma unroll
  for (int nt = 0; nt < 2; ++nt) {
    lacc[nt] = FZ;
#pragma unroll
    for (int dt = 0; dt < 4; ++dt) o[nt][dt] = FZ;
  }

  // prologue: stage K-pairs 0,1 into bufs 0,1 (8 waves x 1KB each)
  stage16(sgK, &sK[0][ldw]);
  stage16(sgK + 8192, &sK[1][ldw]);

#define COMPUTE(SK, VF) do {                                                    \
    bf16x8 ka[2][2];                                                            \
    ka[0][0] = *(const bf16x8*)&(SK)[av];                                       \
    ka[0][1] = *(const bf16x8*)&(SK)[av + 512];                                 \
    ka[1][0] = *(const bf16x8*)&(SK)[av + 1024];                                \
    ka[1][1] = *(const bf16x8*)&(SK)[av + 1536];                                \
    floatx4 st[2][2];                                                           \
    _Pragma("unroll")                                                           \
    for (int nt = 0; nt < 2; ++nt)                                              \
      _Pragma("unroll")                                                         \
      for (int t = 0; t < 2; ++t)                                               \
        st[nt][t] = MFMA16(ka[t][1], qf[nt][1], MFMA16(ka[t][0], qf[nt][0], FZ)); \
    bf16x8 pb[2];                                                               \
    _Pragma("unroll")                                                           \
    for (int nt = 0; nt < 2; ++nt) {                                            \
      float pp[8];                                                              \
      _Pragma("unroll")                                                         \
      for (int t = 0; t < 2; ++t)                                               \
        _Pragma("unroll")                                                       \
        for (int r = 0; r < 4; ++r) pp[t * 4 + r] = __builtin_amdgcn_exp2f(st[nt][t][r]); \
      union { __hip_bfloat162 h2[4]; bf16x8 v8; } u;                            \
      u.h2[0] = __float22bfloat162_rn(float2{pp[0], pp[1]});                    \
      u.h2[1] = __float22bfloat162_rn(float2{pp[2], pp[3]});                    \
      u.h2[2] = __float22bfloat162_rn(float2{pp[4], pp[5]});                    \
      u.h2[3] = __float22bfloat162_rn(float2{pp[6], pp[7]});                    \
      pb[nt] = u.v8;                                                            \
    }                                                                           \
    _Pragma("unroll")                                                           \
    for (int nt = 0; nt < 2; ++nt) {                                            \
      lacc[nt] = MFMA16(ones, pb[nt], lacc[nt]);                                \
      _Pragma("unroll")                                                         \
      for (int dt = 0; dt < 4; ++dt)                                            \
        o[nt][dt] = MFMA16((VF)[dt], pb[nt], o[nt][dt]);                        \
    }                                                                           \
  } while (0)

  short* c0 = sK[0]; short* c1 = sK[1];   // compute bufs this step
  short* n0 = sK[2]; short* n1 = sK[3];   // stage bufs this step

  for (int s = 0; s < 32; ++s) {
    // all outstanding stage16 landed; this wave's prior ds_reads complete.
    asm volatile("s_waitcnt vmcnt(0) lgkmcnt(0)" ::: "memory");
    __builtin_amdgcn_s_barrier();

    // V loads for this step's two groups — BEFORE the stage16s, so the
    // compiler's pre-PV waits leave the K staging in flight.
    const short* v0p = gV + (size_t)(4 * s + half) * 4096;
    const short* v1p = gV + (size_t)(4 * s + 2 + half) * 4096;
    bf16x8 vf0[4], vf1[4];
    vf0[0] = *(const bf16x8*)(v0p);
    vf0[1] = *(const bf16x8*)(v0p + 512);
    vf0[2] = *(const bf16x8*)(v0p + 1024);
    vf0[3] = *(const bf16x8*)(v0p + 1536);
    vf1[0] = *(const bf16x8*)(v1p);
    vf1[1] = *(const bf16x8*)(v1p + 512);
    vf1[2] = *(const bf16x8*)(v1p + 1024);
    vf1[3] = *(const bf16x8*)(v1p + 1536);

    if (s < 31) {    // stage K-pairs 2s+2, 2s+3 into the other two bufs
      const short* gs = sgK + (size_t)(s + 1) * 16384;
      stage16(gs, n0 + ldw);
      stage16(gs + 8192, n1 + ldw);
    }

    __builtin_amdgcn_s_setprio(1);
    { const short* SK = c0 + (half << 11); COMPUTE(SK, vf0); }  // group 4s+half
    { const short* SK = c1 + (half << 11); COMPUTE(SK, vf1); }  // group 4s+2+half
    __builtin_amdgcn_s_setprio(0);

    short* t;
    t = c0; c0 = n0; n0 = t;
    t = c1; c1 = n1; n1 = t;
  }
#undef COMPUTE

  // ---- combine halves through comb (half=1 publishes, half=0 finishes) ----
  __syncthreads();
  if (half) {
    float* c = comb[wq][lane];
#pragma unroll
    for (int nt = 0; nt < 2; ++nt) {
#pragma unroll
      for (int dt = 0; dt < 4; ++dt)
#pragma unroll
        for (int r = 0; r < 4; ++r) c[nt * 16 + dt * 4 + r] = o[nt][dt][r];
      c[32 + nt] = lacc[nt][0];
    }
  }
  __syncthreads();
  if (!half) {
    const float* c = comb[wq][lane];
    const int b = bh >> 3, h = bh & 7;
#pragma unroll
    for (int nt = 0; nt < 2; ++nt) {
      const float inv = 1.0f / (lacc[nt][0] + c[32 + nt]);
      const int row = qrow0 + nt * 16 + l15;
      short* cp = ctx + (size_t)(b * 4096 + row) * 512 + h * 64 + quad * 4;
#pragma unroll
      for (int dt = 0; dt < 4; ++dt) {
        union { __hip_bfloat162 h2[2]; shortx4 s4; } u;
        u.h2[0] = __float22bfloat162_rn(
            float2{(o[nt][dt][0] + c[nt * 16 + dt * 4 + 0]) * inv,
                   (o[nt][dt][1] + c[nt * 16 + dt * 4 + 1]) * inv});
        u.h2[1] = __float22bfloat162_rn(
            float2{(o[nt][dt][2] + c[nt * 16 + dt * 4 + 2]) * inv,
                   (o[nt][dt][3] + c[nt * 16 + dt * 4 + 3]) * inv});
        *(shortx4*)(cp + dt * 16) = u.s4;
      }
    }
  }
}

// ---------------------------------------------------------------------------
extern "C" void kernel_launch(void* const* d_in, const int* in_sizes, int n_in,
                              void* d_out, int out_size, void* d_ws, size_t ws_size,
                              hipStream_t stream) {
  const float* q  = (const float*)d_in[0];
  const float* k  = (const float*)d_in[1];
  const float* v  = (const float*)d_in[2];
  const float* Wq = (const float*)d_in[3];
  const float* bq = (const float*)d_in[4];
  const float* Wk = (const float*)d_in[5];
  const float* bk = (const float*)d_in[6];
  const float* Wv = (const float*)d_in[7];
  const float* bv = (const float*)d_in[8];
  const float* Wo = (const float*)d_in[9];
  const float* bo = (const float*)d_in[10];

  const int XN = 2 * 4096 * 512;
  const int WN = 512 * 512;

  short* ws  = (short*)d_ws;
  short* xqb = ws;                       // q/k/v bf16 (contiguous for cvt3)
  short* xkb = ws + (size_t)XN;
  short* xvb = ws + (size_t)2 * XN;
  short* wqb = ws + (size_t)3 * XN;      // weights bf16 (contiguous for cvtw)
  short* wkb = wqb + WN;
  short* wvb = wkb + WN;
  short* wob = wvb + WN;
  short* Qh  = wob + WN;
  short* KVf = Qh + (size_t)XN;          // fragment-ordered K+V: 2*XN shorts
  short* ctx = xqb;                      // xq dead after projections

  dim3 cg(XN / 4 / 256, 3);
  cvt3_kernel<<<cg, 256, 0, stream>>>(q, k, v, xqb, XN / 4);
  dim3 wg(WN / 4 / 256, 4);
  cvtw_kernel<<<wg, 256, 0, stream>>>(Wq, Wk, Wv, Wo, wqb, WN / 4);

  dim3 pg(64, 8, 3);
  proj3_kernel<<<pg, 256, 0, stream>>>(xqb, xkb, xvb, wqb, wkb, wvb,
                                       bq, bk, bv, Qh, KVf);

  flash_kernel<<<512, 512, 0, stream>>>(Qh, KVf, ctx);

  dim3 og(64, 8);
  proj_o_kernel<<<og, 256, 0, stream>>>(ctx, wob, bo, (float*)d_out);
}

// Round 8
// 214.415 us; speedup vs baseline: 1.1456x; 1.1456x over previous
//
#include <hip/hip_runtime.h>
#include <hip/hip_bf16.h>
#include <stdint.h>

// ---------------------------------------------------------------------------
// MHA: B=2, S=4096, D=512, H=8, dk=64.
// R17:
//  * flash: exact R15 revert (67.4 µs proven; R16's V-from-L2 exposed ~200cy
//    L2 latency per step and regressed to 107).
//  * proj3/proj_o: epilogue-through-LDS. MFMA loop unchanged; instead of
//    scalar 2B/4B scattered global stores, acc is scattered into a 16KB LDS
//    image in destination order (cheap ds_writes), then streamed out as
//    4 x 16B coalesced stores per thread. Index algebra per block:
//    g_local=wave, K: l15b=quad*4, tt=mt; V: quadv=quad, jv=mt*4 (r contig);
//    Q image [row_local][64]; proj_o 2 mt-passes of a 64x64 fp32 image.
// ---------------------------------------------------------------------------

typedef float  floatx4 __attribute__((ext_vector_type(4)));
typedef __bf16 bf16x8  __attribute__((ext_vector_type(8)));
typedef short  shortx4 __attribute__((ext_vector_type(4)));
typedef short  shortx8 __attribute__((ext_vector_type(8)));

#define MFMA16(a, b, c) __builtin_amdgcn_mfma_f32_16x16x32_bf16((a), (b), (c), 0, 0, 0)

// folded into Q projection: (1/sqrt(64)) * log2(e)  -> scores in log2 domain
#define QSCALE 0.1803368801111244f

__device__ __forceinline__ short f2bf(float f) {   // RNE
  union { float f; uint32_t u; } a; a.f = f;
  uint32_t u = a.u;
  u += 0x7fffu + ((u >> 16) & 1u);
  return (short)(u >> 16);
}

// async global->LDS, 16B per lane; lds dest = wave-uniform base + lane*16
__device__ __forceinline__ void stage16(const short* g, short* l) {
  __builtin_amdgcn_global_load_lds(
      (const __attribute__((address_space(1))) void*)g,
      (__attribute__((address_space(3))) void*)l, 16, 0, 0);
}

// ---------------------------------------------------------------------------
// fp32 -> bf16 activations (q,k,v), blockIdx.y picks tensor
// ---------------------------------------------------------------------------
__global__ __launch_bounds__(256) void cvt3_kernel(const float* __restrict__ q,
                                                   const float* __restrict__ k,
                                                   const float* __restrict__ v,
                                                   short* __restrict__ out, int n4) {
  const int which = blockIdx.y;
  const float* in = which == 0 ? q : which == 1 ? k : v;
  short* o = out + (size_t)which * (size_t)n4 * 4;
  int i = blockIdx.x * 256 + threadIdx.x;
  if (i < n4) {
    float4 f = reinterpret_cast<const float4*>(in)[i];
    shortx4 s;
    s.x = f2bf(f.x); s.y = f2bf(f.y); s.z = f2bf(f.z); s.w = f2bf(f.w);
    reinterpret_cast<shortx4*>(o)[i] = s;
  }
}

// weights fp32 -> bf16, blockIdx.y picks tensor
__global__ __launch_bounds__(256) void cvtw_kernel(const float* __restrict__ w0,
                                                   const float* __restrict__ w1,
                                                   const float* __restrict__ w2,
                                                   const float* __restrict__ w3,
                                                   short* __restrict__ out, int n4) {
  const int which = blockIdx.y;
  const float* in = which == 0 ? w0 : which == 1 ? w1 : which == 2 ? w2 : w3;
  short* o = out + (size_t)which * (size_t)n4 * 4;
  int i = blockIdx.x * 256 + threadIdx.x;
  if (i < n4) {
    float4 f = reinterpret_cast<const float4*>(in)[i];
    shortx4 s;
    s.x = f2bf(f.x); s.y = f2bf(f.y); s.z = f2bf(f.z); s.w = f2bf(f.w);
    reinterpret_cast<shortx4*>(o)[i] = s;
  }
}

// ---------------------------------------------------------------------------
// Fused Q/K/V projection. blockIdx.z picks tensor. A[8192,512] x W[512,512]^T.
// 128x64 tile, BK=32, double-buffered LDS (global_load_lds, 1 barrier/iter),
// XOR-swizzled fragment reads. Epilogue through LDS (coalesced stores).
// ---------------------------------------------------------------------------
__global__ __launch_bounds__(256) void proj3_kernel(
    const short* __restrict__ xq, const short* __restrict__ xk, const short* __restrict__ xv,
    const short* __restrict__ wq, const short* __restrict__ wk, const short* __restrict__ wv,
    const float* __restrict__ bq, const float* __restrict__ bk, const float* __restrict__ bv,
    short* __restrict__ Qh, short* __restrict__ KV) {
  const int which = blockIdx.z;
  const short* A = which == 0 ? xq : which == 1 ? xk : xv;
  const short* W = which == 0 ? wq : which == 1 ? wk : wv;
  const float* bias = which == 0 ? bq : which == 1 ? bk : bv;

  __shared__ __align__(16) short sA[2][4096];   // [128][32] swizzled; reused as epilogue image
  __shared__ __align__(16) short sB[2][2048];   // [64][32] swizzled

  const int K = 512;
  const int tid = threadIdx.x;
  const int lane = tid & 63;
  const int wave = tid >> 6;
  const int l15 = lane & 15;
  const int quad = lane >> 4;
  const int tileM = blockIdx.x * 128;
  const int tileN = blockIdx.y * 64;

  const int srow = tid >> 2;                       // 0..63
  const int fr = (srow ^ (srow >> 2)) & 3;         // same for srow+64
  const int sq = ((tid & 3) ^ fr) * 8;
  const short* As0 = A + (size_t)(tileM + srow) * K + sq;        // rows 0..63
  const short* As1 = As0 + (size_t)64 * K;                       // rows 64..127
  const short* Bs  = W + (size_t)(tileN + srow) * K + sq;
  const int ldw = wave * 512;                      // wave-uniform LDS slice (shorts)

  const int fl = (l15 ^ (l15 >> 2)) & 3;
  const int qsw = (quad ^ fl) * 8;
  const int ra0 = (wave * 32 + l15) * 32 + qsw;    // A frag mt=0
  const int ra1 = ra0 + 512;                       // mt=1 (+16 rows)
  const int rb0 = l15 * 32 + qsw;                  // B frag (+ nt*512)

  floatx4 acc[2][4];
#pragma unroll
  for (int mt = 0; mt < 2; ++mt)
#pragma unroll
    for (int nt = 0; nt < 4; ++nt) acc[mt][nt] = (floatx4){0.f, 0.f, 0.f, 0.f};

  // prologue: stage k-slice 0 into buffer 0
  stage16(As0, &sA[0][ldw]);
  stage16(As1, &sA[0][2048 + ldw]);
  stage16(Bs,  &sB[0][ldw]);

#pragma unroll 2
  for (int t = 0; t < 16; ++t) {
    __syncthreads();                 // drains own stage vmcnt + block sync
    if (t != 15) {                   // stage next slice into other buffer
      const int kk = (t + 1) * 32;
      short* a_ld = &sA[(t + 1) & 1][ldw];
      stage16(As0 + kk, a_ld);
      stage16(As1 + kk, a_ld + 2048);
      stage16(Bs + kk, &sB[(t + 1) & 1][ldw]);
    }
    const short* sa = sA[t & 1];
    const short* sb = sB[t & 1];
    bf16x8 a0 = *(const bf16x8*)&sa[ra0];
    bf16x8 a1 = *(const bf16x8*)&sa[ra1];
#pragma unroll
    for (int nt = 0; nt < 4; ++nt) {
      bf16x8 wf = *(const bf16x8*)&sb[rb0 + nt * 512];
      acc[0][nt] = MFMA16(a0, wf, acc[0][nt]);
      acc[1][nt] = MFMA16(a1, wf, acc[1][nt]);
    }
  }

  // ---- epilogue through LDS: build 16KB destination-ordered image ----
  __syncthreads();                     // all k-loop LDS reads complete
  short* sE = &sA[0][0];               // 8192 shorts = 16 KB
  const int b = tileM >> 12, s0 = tileM & 4095;
  const int h = tileN >> 6;            // tileN 64-wide => single head
  const int g0 = s0 >> 5;

  if (which == 0) {
    // Q image: [row_local][d], row_local = wave*32 + mt*16 + quad*4 + r
#pragma unroll
    for (int mt = 0; mt < 2; ++mt)
#pragma unroll
      for (int nt = 0; nt < 4; ++nt) {
        const float bc = bias[tileN + nt * 16 + l15];
        const int d = nt * 16 + l15;
        short* p = sE + (wave * 32 + mt * 16 + quad * 4) * 64 + d;
#pragma unroll
        for (int r = 0; r < 4; ++r) p[r * 64] = f2bf((acc[mt][nt][r] + bc) * QSCALE);
      }
    __syncthreads();
    short* dst = Qh + ((size_t)(b * 8 + h) * 4096 + s0) * 64;
#pragma unroll
    for (int k = 0; k < 4; ++k) {
      const int L = (k * 256 + tid) * 8;     // consecutive lanes -> consecutive 16B
      *(shortx8*)(dst + L) = *(const shortx8*)(sE + L);
    }
  } else if (which == 1) {
    // K image: [g_local=wave][2048]: (mt*2+ks)*512 + quadk*128 + (quad*4+r)*8 + jj
#pragma unroll
    for (int mt = 0; mt < 2; ++mt)
#pragma unroll
      for (int nt = 0; nt < 4; ++nt) {
        const int dd = nt * 16 + l15;
        const int ks = dd >> 5, quadk = (dd >> 3) & 3, jj = dd & 7;
        const float bc = bias[tileN + dd];
        short* p = sE + wave * 2048 + (mt * 2 + ks) * 512 + quadk * 128 + quad * 32 + jj;
#pragma unroll
        for (int r = 0; r < 4; ++r) p[r * 8] = f2bf(acc[mt][nt][r] + bc);
      }
    __syncthreads();
    short* dst = KV + ((size_t)(b * 8 + h) * 128 + g0) * 4096;
#pragma unroll
    for (int k = 0; k < 4; ++k) {
      const int L = (k * 256 + tid) * 8;
      *(shortx8*)(dst + (size_t)(L >> 11) * 4096 + (L & 2047)) = *(const shortx8*)(sE + L);
    }
  } else {
    // V image: [g_local=wave][2048]: nt*512 + quad*128 + l15*8 + mt*4 + r
#pragma unroll
    for (int mt = 0; mt < 2; ++mt)
#pragma unroll
      for (int nt = 0; nt < 4; ++nt) {
        const float bc = bias[tileN + nt * 16 + l15];
        shortx4 pv;
        pv.x = f2bf(acc[mt][nt][0] + bc);
        pv.y = f2bf(acc[mt][nt][1] + bc);
        pv.z = f2bf(acc[mt][nt][2] + bc);
        pv.w = f2bf(acc[mt][nt][3] + bc);
        *(shortx4*)(sE + wave * 2048 + nt * 512 + quad * 128 + l15 * 8 + mt * 4) = pv;
      }
    __syncthreads();
    short* dst = KV + ((size_t)(b * 8 + h) * 128 + g0) * 4096 + 2048;
#pragma unroll
    for (int k = 0; k < 4; ++k) {
      const int L = (k * 256 + tid) * 8;
      *(shortx8*)(dst + (size_t)(L >> 11) * 4096 + (L & 2047)) = *(const shortx8*)(sE + L);
    }
  }
}

// ---------------------------------------------------------------------------
// Output projection: ctx bf16 [8192,512] x Wo^T + bo -> fp32 out. 128x64.
// Epilogue through LDS, 2 mt-passes of a 64x64 fp32 image.
// ---------------------------------------------------------------------------
__global__ __launch_bounds__(256) void proj_o_kernel(
    const short* __restrict__ A, const short* __restrict__ W,
    const float* __restrict__ bias, float* __restrict__ out) {
  __shared__ __align__(16) short sA[2][4096];
  __shared__ __align__(16) short sB[2][2048];

  const int K = 512;
  const int tid = threadIdx.x;
  const int lane = tid & 63;
  const int wave = tid >> 6;
  const int l15 = lane & 15;
  const int quad = lane >> 4;
  const int tileM = blockIdx.x * 128;
  const int tileN = blockIdx.y * 64;

  const int srow = tid >> 2;
  const int fr = (srow ^ (srow >> 2)) & 3;
  const int sq = ((tid & 3) ^ fr) * 8;
  const short* As0 = A + (size_t)(tileM + srow) * K + sq;
  const short* As1 = As0 + (size_t)64 * K;
  const short* Bs  = W + (size_t)(tileN + srow) * K + sq;
  const int ldw = wave * 512;

  const int fl = (l15 ^ (l15 >> 2)) & 3;
  const int qsw = (quad ^ fl) * 8;
  const int ra0 = (wave * 32 + l15) * 32 + qsw;
  const int ra1 = ra0 + 512;
  const int rb0 = l15 * 32 + qsw;

  floatx4 acc[2][4];
#pragma unroll
  for (int mt = 0; mt < 2; ++mt)
#pragma unroll
    for (int nt = 0; nt < 4; ++nt) acc[mt][nt] = (floatx4){0.f, 0.f, 0.f, 0.f};

  stage16(As0, &sA[0][ldw]);
  stage16(As1, &sA[0][2048 + ldw]);
  stage16(Bs,  &sB[0][ldw]);

#pragma unroll 2
  for (int t = 0; t < 16; ++t) {
    __syncthreads();
    if (t != 15) {
      const int kk = (t + 1) * 32;
      short* a_ld = &sA[(t + 1) & 1][ldw];
      stage16(As0 + kk, a_ld);
      stage16(As1 + kk, a_ld + 2048);
      stage16(Bs + kk, &sB[(t + 1) & 1][ldw]);
    }
    const short* sa = sA[t & 1];
    const short* sb = sB[t & 1];
    bf16x8 a0 = *(const bf16x8*)&sa[ra0];
    bf16x8 a1 = *(const bf16x8*)&sa[ra1];
#pragma unroll
    for (int nt = 0; nt < 4; ++nt) {
      bf16x8 wf = *(const bf16x8*)&sb[rb0 + nt * 512];
      acc[0][nt] = MFMA16(a0, wf, acc[0][nt]);
      acc[1][nt] = MFMA16(a1, wf, acc[1][nt]);
    }
  }

  // ---- epilogue through LDS: 2 passes of 64x64 fp32 (16 KB) ----
  float* sO = (float*)&sA[0][0];       // 4096 floats = 16 KB
#pragma unroll
  for (int mt = 0; mt < 2; ++mt) {
    __syncthreads();                   // pass 0: k-loop reads done; pass 1: stores done
    // compressed row cr = wave*16 + quad*4 + r  <->  row = (cr>>4)*32 + mt*16 + (cr&15)
#pragma unroll
    for (int nt = 0; nt < 4; ++nt) {
      const float bc = bias[tileN + nt * 16 + l15];
      float* p = sO + (wave * 16 + quad * 4) * 64 + nt * 16 + l15;
#pragma unroll
      for (int r = 0; r < 4; ++r) p[r * 64] = acc[mt][nt][r] + bc;
    }
    __syncthreads();
#pragma unroll
    for (int k = 0; k < 4; ++k) {
      const int L = (k * 256 + tid) * 4;       // 16B chunks, lanes consecutive
      const int cr = L >> 6, c = L & 63;
      const int row = (cr >> 4) * 32 + mt * 16 + (cr & 15);
      *(float4*)(out + (size_t)(tileM + row) * 512 + tileN + c) = *(const float4*)(sO + L);
    }
  }
}

// ---------------------------------------------------------------------------
// Flash attention: R15-proven. 8 waves (4 qg x 2 key-half), quad-buffered LDS,
// 2 pairs per barrier: vmcnt(0)+lgkmcnt(0) -> s_barrier -> stage 32KB ->
// setprio(1) COMPUTE x2 setprio(0). RNE pack via __float22bfloat162_rn.
// Combine-through-LDS (aliases sKV after the loop drains).
// ---------------------------------------------------------------------------
__global__ __launch_bounds__(512) void flash_kernel(
    const short* __restrict__ Qh, const short* __restrict__ KV,
    short* __restrict__ ctx) {
  __shared__ __align__(16) short sKV[4][8192];   // 4 bufs x 16KB pairs (64KB)

  const int id = blockIdx.x;          // 0..511
  const int xcd = id & 7;
  const int j = id >> 3;              // 0..63
  const int bh = xcd + ((j >> 5) << 3);
  const int qtile = j & 31;

  const int tid = threadIdx.x;
  const int wave = tid >> 6;          // 0..7
  const int lane = tid & 63;
  const int l15 = lane & 15;
  const int quad = lane >> 4;
  const int wq = wave & 3;            // q-row group within block
  const int half = wave >> 2;         // key half: 0 -> even groups, 1 -> odd
  const int qrow0 = qtile * 128 + wq * 32;

  // Q B-frags: B[k=d=quad*8+i+32ks][n=qrow=l15]
  bf16x8 qf[2][2];
#pragma unroll
  for (int nt = 0; nt < 2; ++nt) {
    const short* Qb = Qh + (size_t)(bh * 4096 + qrow0 + nt * 16 + l15) * 64 + quad * 8;
    qf[nt][0] = *(const bf16x8*)(Qb);
    qf[nt][1] = *(const bf16x8*)(Qb + 32);
  }

  // ones A-fragment (bf16 1.0 = 0x3F80) for MFMA row-sums
  bf16x8 ones;
  {
    union { short s[8]; bf16x8 v; } u;
#pragma unroll
    for (int i = 0; i < 8; ++i) u.s[i] = (short)0x3F80;
    ones = u.v;
  }

  const short* KVb = KV + (size_t)bh * (128 * 4096);
  const short* sg = KVb + wave * 512 + lane * 8;    // staging src (wave slice)
  const int ldw = wave * 512;                       // wave-uniform LDS dest offset
  const int av = lane * 8;                          // lane-ordered chunk address

  const floatx4 FZ = (floatx4){0.f, 0.f, 0.f, 0.f};
  floatx4 o[2][4];
  floatx4 lacc[2];
#pragma unroll
  for (int nt = 0; nt < 2; ++nt) {
    lacc[nt] = FZ;
#pragma unroll
    for (int dt = 0; dt < 4; ++dt) o[nt][dt] = FZ;
  }

  // prologue: stage pairs 0,1 into bufs 0,1 (8 waves x 4 x 1KB = 32KB)
  stage16(sg, &sKV[0][ldw]);
  stage16(sg + 4096, &sKV[0][ldw + 4096]);
  stage16(sg + 8192, &sKV[1][ldw]);
  stage16(sg + 12288, &sKV[1][ldw + 4096]);

#define COMPUTE(S) do {                                                         \
    bf16x8 ka[2][2], vf[4];                                                     \
    ka[0][0] = *(const bf16x8*)&(S)[av];                                        \
    ka[0][1] = *(const bf16x8*)&(S)[av + 512];                                  \
    ka[1][0] = *(const bf16x8*)&(S)[av + 1024];                                 \
    ka[1][1] = *(const bf16x8*)&(S)[av + 1536];                                 \
    vf[0] = *(const bf16x8*)&(S)[av + 2048];                                    \
    vf[1] = *(const bf16x8*)&(S)[av + 2560];                                    \
    vf[2] = *(const bf16x8*)&(S)[av + 3072];                                    \
    vf[3] = *(const bf16x8*)&(S)[av + 3584];                                    \
    floatx4 st[2][2];                                                           \
    _Pragma("unroll")                                                           \
    for (int nt = 0; nt < 2; ++nt)                                              \
      _Pragma("unroll")                                                         \
      for (int t = 0; t < 2; ++t)                                               \
        st[nt][t] = MFMA16(ka[t][1], qf[nt][1], MFMA16(ka[t][0], qf[nt][0], FZ)); \
    bf16x8 pb[2];                                                               \
    _Pragma("unroll")                                                           \
    for (int nt = 0; nt < 2; ++nt) {                                            \
      float pp[8];                                                              \
      _Pragma("unroll")                                                         \
      for (int t = 0; t < 2; ++t)                                               \
        _Pragma("unroll")                                                       \
        for (int r = 0; r < 4; ++r) pp[t * 4 + r] = __builtin_amdgcn_exp2f(st[nt][t][r]); \
      union { __hip_bfloat162 h2[4]; bf16x8 v8; } u;                            \
      u.h2[0] = __float22bfloat162_rn(float2{pp[0], pp[1]});                    \
      u.h2[1] = __float22bfloat162_rn(float2{pp[2], pp[3]});                    \
      u.h2[2] = __float22bfloat162_rn(float2{pp[4], pp[5]});                    \
      u.h2[3] = __float22bfloat162_rn(float2{pp[6], pp[7]});                    \
      pb[nt] = u.v8;                                                            \
    }                                                                           \
    _Pragma("unroll")                                                           \
    for (int nt = 0; nt < 2; ++nt) {                                            \
      lacc[nt] = MFMA16(ones, pb[nt], lacc[nt]);                                \
      _Pragma("unroll")                                                         \
      for (int dt = 0; dt < 4; ++dt)                                            \
        o[nt][dt] = MFMA16(vf[dt], pb[nt], o[nt][dt]);                          \
    }                                                                           \
  } while (0)

  short* c0 = sKV[0]; short* c1 = sKV[1];   // compute bufs this step
  short* n0 = sKV[2]; short* n1 = sKV[3];   // stage bufs this step

  for (int s = 0; s < 32; ++s) {
    // all 4 outstanding stage16 must have landed; lgkmcnt(0): this wave's
    // ds_reads of the bufs about to be restaged are complete.
    asm volatile("s_waitcnt vmcnt(0) lgkmcnt(0)" ::: "memory");
    __builtin_amdgcn_s_barrier();

    if (s < 31) {    // stage pairs 2s+2, 2s+3 into the other two bufs
      const short* gs = sg + (size_t)(s + 1) * 16384;
      stage16(gs, n0 + ldw);
      stage16(gs + 4096, n0 + ldw + 4096);
      stage16(gs + 8192, n1 + ldw);
      stage16(gs + 12288, n1 + ldw + 4096);
    }

    __builtin_amdgcn_s_setprio(1);
    { const short* S = c0 + (half << 12); COMPUTE(S); }   // group 4s + half
    { const short* S = c1 + (half << 12); COMPUTE(S); }   // group 4s + 2 + half
    __builtin_amdgcn_s_setprio(0);

    short* t;
    t = c0; c0 = n0; n0 = t;
    t = c1; c1 = n1; n1 = t;
  }
#undef COMPUTE

  // ---- combine halves through sKV-as-float scratch (loop done) ----
  __syncthreads();                     // drains lgkm + block sync
  float* cb = (float*)sKV;             // 4 qg x 64 lanes x 34 floats = 34.8KB
  if (half) {
    float* c = cb + (size_t)(wq * 64 + lane) * 34;
#pragma unroll
    for (int nt = 0; nt < 2; ++nt) {
#pragma unroll
      for (int dt = 0; dt < 4; ++dt)
#pragma unroll
        for (int r = 0; r < 4; ++r) c[nt * 16 + dt * 4 + r] = o[nt][dt][r];
      c[32 + nt] = lacc[nt][0];
    }
  }
  __syncthreads();
  if (!half) {
    const float* c = cb + (size_t)(wq * 64 + lane) * 34;
    const int b = bh >> 3, h = bh & 7;
#pragma unroll
    for (int nt = 0; nt < 2; ++nt) {
      const float inv = 1.0f / (lacc[nt][0] + c[32 + nt]);
      const int row = qrow0 + nt * 16 + l15;
      short* cp = ctx + (size_t)(b * 4096 + row) * 512 + h * 64 + quad * 4;
#pragma unroll
      for (int dt = 0; dt < 4; ++dt) {
        union { __hip_bfloat162 h2[2]; shortx4 s4; } u;
        u.h2[0] = __float22bfloat162_rn(
            float2{(o[nt][dt][0] + c[nt * 16 + dt * 4 + 0]) * inv,
                   (o[nt][dt][1] + c[nt * 16 + dt * 4 + 1]) * inv});
        u.h2[1] = __float22bfloat162_rn(
            float2{(o[nt][dt][2] + c[nt * 16 + dt * 4 + 2]) * inv,
                   (o[nt][dt][3] + c[nt * 16 + dt * 4 + 3]) * inv});
        *(shortx4*)(cp + dt * 16) = u.s4;
      }
    }
  }
}

// ---------------------------------------------------------------------------
extern "C" void kernel_launch(void* const* d_in, const int* in_sizes, int n_in,
                              void* d_out, int out_size, void* d_ws, size_t ws_size,
                              hipStream_t stream) {
  const float* q  = (const float*)d_in[0];
  const float* k  = (const float*)d_in[1];
  const float* v  = (const float*)d_in[2];
  const float* Wq = (const float*)d_in[3];
  const float* bq = (const float*)d_in[4];
  const float* Wk = (const float*)d_in[5];
  const float* bk = (const float*)d_in[6];
  const float* Wv = (const float*)d_in[7];
  const float* bv = (const float*)d_in[8];
  const float* Wo = (const float*)d_in[9];
  const float* bo = (const float*)d_in[10];

  const int XN = 2 * 4096 * 512;
  const int WN = 512 * 512;

  short* ws  = (short*)d_ws;
  short* xqb = ws;                       // q/k/v bf16 (contiguous for cvt3)
  short* xkb = ws + (size_t)XN;
  short* xvb = ws + (size_t)2 * XN;
  short* wqb = ws + (size_t)3 * XN;      // weights bf16 (contiguous for cvtw)
  short* wkb = wqb + WN;
  short* wvb = wkb + WN;
  short* wob = wvb + WN;
  short* Qh  = wob + WN;
  short* KVf = Qh + (size_t)XN;          // fragment-ordered K+V: 2*XN shorts
  short* ctx = xqb;                      // xq dead after projections

  dim3 cg(XN / 4 / 256, 3);
  cvt3_kernel<<<cg, 256, 0, stream>>>(q, k, v, xqb, XN / 4);
  dim3 wg(WN / 4 / 256, 4);
  cvtw_kernel<<<wg, 256, 0, stream>>>(Wq, Wk, Wv, Wo, wqb, WN / 4);

  dim3 pg(64, 8, 3);
  proj3_kernel<<<pg, 256, 0, stream>>>(xqb, xkb, xvb, wqb, wkb, wvb,
                                       bq, bk, bv, Qh, KVf);

  flash_kernel<<<512, 512, 0, stream>>>(Qh, KVf, ctx);

  dim3 og(64, 8);
  proj_o_kernel<<<og, 256, 0, stream>>>(ctx, wob, bo, (float*)d_out);
}